// Round 1
// baseline (297.526 us; speedup 1.0000x reference)
//
#include <hip/hip_runtime.h>

#define N_NODES 512
#define N_EDGES (512 * 512)

// ---------------- utility: zero int buffer ----------------
__global__ void zero_k(int* __restrict__ p, int n) {
  int i = blockIdx.x * blockDim.x + threadIdx.x;
  if (i < n) p[i] = 0;
}

// ---------------- histogram of dst ----------------
__global__ void hist_k(const int* __restrict__ dst, int* __restrict__ counts) {
  __shared__ int lh[N_NODES];
  for (int i = threadIdx.x; i < N_NODES; i += blockDim.x) lh[i] = 0;
  __syncthreads();
  const int stride = gridDim.x * blockDim.x;
  for (int e = blockIdx.x * blockDim.x + threadIdx.x; e < N_EDGES; e += stride)
    atomicAdd(&lh[dst[e]], 1);
  __syncthreads();
  for (int i = threadIdx.x; i < N_NODES; i += blockDim.x) {
    int c = lh[i];
    if (c) atomicAdd(&counts[i], c);
  }
}

// ---------------- exclusive scan over 512 counts (1 block) ----------------
__global__ void scan_k(const int* __restrict__ counts, int* __restrict__ offsets,
                       int* __restrict__ cursor) {
  __shared__ int tmp[N_NODES];
  const int t = threadIdx.x;
  const int c = counts[t];
  tmp[t] = c;
  __syncthreads();
  for (int d = 1; d < N_NODES; d <<= 1) {
    int add = (t >= d) ? tmp[t - d] : 0;
    __syncthreads();
    tmp[t] += add;
    __syncthreads();
  }
  offsets[t + 1] = tmp[t];
  if (t == 0) offsets[0] = 0;
  cursor[t] = tmp[t] - c;  // exclusive prefix
}

// ---------------- scatter edge ids into CSR buckets ----------------
__global__ void scatter_k(const int* __restrict__ dst, int* __restrict__ cursor,
                          int* __restrict__ perm) {
  const int e = blockIdx.x * blockDim.x + threadIdx.x;
  if (e < N_EDGES) {
    const int p = atomicAdd(&cursor[dst[e]], 1);
    perm[p] = e;
  }
}

// ---------------- fused NNConv layer: block per dst node ----------------
// out_i = relu( mean_{e: dst=i} ( h[src_e] @ relu(ea_e @ W + b) )  + h_i @ root + bias )
template <int IN, int OUT>
__launch_bounds__(256)
__global__ void conv_k(const float* __restrict__ hprev,   // [N, IN]
                       const float* __restrict__ ea,      // [E, 6]
                       const int* __restrict__ src,       // [E]
                       const int* __restrict__ perm,      // [E] edge ids sorted by dst
                       const int* __restrict__ offsets,   // [N+1]
                       const float* __restrict__ W,       // [6, IN*OUT]
                       const float* __restrict__ bvec,    // [IN*OUT]
                       const float* __restrict__ root,    // [IN, OUT]
                       const float* __restrict__ bias,    // [OUT]
                       float* __restrict__ hnext) {       // [N, OUT]
  constexpr int KK = IN * OUT;
  __shared__ float Wt[KK * 8];       // [k][0..5]=W[v][k], [6]=b[k], [7]=pad
  __shared__ float red[4][OUT];

  const int node = blockIdx.x;

  for (int k = threadIdx.x; k < KK; k += blockDim.x) {
#pragma unroll
    for (int v = 0; v < 6; v++) Wt[k * 8 + v] = W[v * KK + k];
    Wt[k * 8 + 6] = bvec[k];
    Wt[k * 8 + 7] = 0.f;
  }
  __syncthreads();

  const int off = offsets[node];
  const int cnt = offsets[node + 1] - off;

  float acc[OUT];
#pragma unroll
  for (int o = 0; o < OUT; o++) acc[o] = 0.f;

  for (int t = threadIdx.x; t < cnt; t += blockDim.x) {
    const int e = perm[off + t];
    const float2 a01 = *reinterpret_cast<const float2*>(ea + e * 6);
    const float2 a23 = *reinterpret_cast<const float2*>(ea + e * 6 + 2);
    const float2 a45 = *reinterpret_cast<const float2*>(ea + e * 6 + 4);
    const float e0 = a01.x, e1 = a01.y, e2 = a23.x, e3 = a23.y, e4 = a45.x, e5 = a45.y;
    const int s = src[e];
    const float* hs = hprev + s * IN;
#pragma unroll 2
    for (int i = 0; i < IN; i++) {
      const float hsi = hs[i];
#pragma unroll
      for (int o = 0; o < OUT; o++) {
        const float4 w0 = *reinterpret_cast<const float4*>(&Wt[(i * OUT + o) * 8]);
        const float4 w1 = *reinterpret_cast<const float4*>(&Wt[(i * OUT + o) * 8 + 4]);
        float th = w1.z;
        th = fmaf(e0, w0.x, th);
        th = fmaf(e1, w0.y, th);
        th = fmaf(e2, w0.z, th);
        th = fmaf(e3, w0.w, th);
        th = fmaf(e4, w1.x, th);
        th = fmaf(e5, w1.y, th);
        acc[o] = fmaf(hsi, fmaxf(th, 0.f), acc[o]);
      }
    }
  }

  // wave reduce, then cross-wave via LDS
  const int lane = threadIdx.x & 63;
  const int wid = threadIdx.x >> 6;
#pragma unroll
  for (int o = 0; o < OUT; o++) {
    float v = acc[o];
#pragma unroll
    for (int d = 32; d > 0; d >>= 1) v += __shfl_down(v, d, 64);
    if (lane == 0) red[wid][o] = v;
  }
  __syncthreads();

  if (threadIdx.x < OUT) {
    const int o = threadIdx.x;
    float sum = red[0][o] + red[1][o] + red[2][o] + red[3][o];
    float agg = sum / fmaxf((float)cnt, 1.f);
    float r = bias[o];
    for (int i = 0; i < IN; i++) r = fmaf(hprev[node * IN + i], root[i * OUT + o], r);
    hnext[node * OUT + o] = fmaxf(agg + r, 0.f);
  }
}

// ---------------- CBT: pairwise L1 over h3 [512, 5] ----------------
__global__ void cbt_k(const float* __restrict__ h3, float* __restrict__ out) {
  __shared__ float sh[N_NODES * 5];
  for (int i = threadIdx.x; i < N_NODES * 5; i += blockDim.x) sh[i] = h3[i];
  __syncthreads();
  const int a = blockIdx.x;
  float ha0 = sh[a * 5 + 0], ha1 = sh[a * 5 + 1], ha2 = sh[a * 5 + 2],
        ha3 = sh[a * 5 + 3], ha4 = sh[a * 5 + 4];
  for (int b = threadIdx.x; b < N_NODES; b += blockDim.x) {
    float s = fabsf(sh[b * 5 + 0] - ha0) + fabsf(sh[b * 5 + 1] - ha1) +
              fabsf(sh[b * 5 + 2] - ha2) + fabsf(sh[b * 5 + 3] - ha3) +
              fabsf(sh[b * 5 + 4] - ha4);
    out[a * N_NODES + b] = s;
  }
}

extern "C" void kernel_launch(void* const* d_in, const int* in_sizes, int n_in,
                              void* d_out, int out_size, void* d_ws, size_t ws_size,
                              hipStream_t stream) {
  const float* x     = (const float*)d_in[0];   // [512,1]
  const float* ea    = (const float*)d_in[1];   // [E,6]
  const int*   ei    = (const int*)d_in[2];     // [2,E]
  const float* W1    = (const float*)d_in[3];
  const float* b1    = (const float*)d_in[4];
  const float* root1 = (const float*)d_in[5];
  const float* bias1 = (const float*)d_in[6];
  const float* W2    = (const float*)d_in[7];
  const float* b2    = (const float*)d_in[8];
  const float* root2 = (const float*)d_in[9];
  const float* bias2 = (const float*)d_in[10];
  const float* W3    = (const float*)d_in[11];
  const float* b3    = (const float*)d_in[12];
  const float* root3 = (const float*)d_in[13];
  const float* bias3 = (const float*)d_in[14];

  const int* src = ei;            // edge_index[0]
  const int* dst = ei + N_EDGES;  // edge_index[1]

  char* ws = (char*)d_ws;
  int* counts  = (int*)(ws + 0);
  int* offsets = (int*)(ws + 8192);
  int* cursor  = (int*)(ws + 16384);
  int* perm    = (int*)(ws + 32768);                       // E ints = 1 MB
  float* h1    = (float*)(ws + 32768 + N_EDGES * 4);       // 512*36
  float* h2    = h1 + N_NODES * 36;                        // 512*24
  float* h3    = h2 + N_NODES * 24;                        // 512*5

  zero_k<<<2, 256, 0, stream>>>(counts, N_NODES);
  hist_k<<<256, 256, 0, stream>>>(dst, counts);
  scan_k<<<1, N_NODES, 0, stream>>>(counts, offsets, cursor);
  scatter_k<<<N_EDGES / 256, 256, 0, stream>>>(dst, cursor, perm);

  conv_k<1, 36><<<N_NODES, 256, 0, stream>>>(x, ea, src, perm, offsets, W1, b1, root1, bias1, h1);
  conv_k<36, 24><<<N_NODES, 256, 0, stream>>>(h1, ea, src, perm, offsets, W2, b2, root2, bias2, h2);
  conv_k<24, 5><<<N_NODES, 256, 0, stream>>>(h2, ea, src, perm, offsets, W3, b3, root3, bias3, h3);

  cbt_k<<<N_NODES, 256, 0, stream>>>(h3, (float*)d_out);
}

// Round 2
// 161.212 us; speedup vs baseline: 1.8456x; 1.8456x over previous
//
#include <hip/hip_runtime.h>

#define N_NODES 512
#define N_EDGES (512 * 512)

// ---------------- utility: zero int buffer ----------------
__global__ void zero_k(int* __restrict__ p, int n) {
  int i = blockIdx.x * blockDim.x + threadIdx.x;
  if (i < n) p[i] = 0;
}

// ---------------- histogram of dst ----------------
__global__ void hist_k(const int* __restrict__ dst, int* __restrict__ counts) {
  __shared__ int lh[N_NODES];
  for (int i = threadIdx.x; i < N_NODES; i += blockDim.x) lh[i] = 0;
  __syncthreads();
  const int stride = gridDim.x * blockDim.x;
  for (int e = blockIdx.x * blockDim.x + threadIdx.x; e < N_EDGES; e += stride)
    atomicAdd(&lh[dst[e]], 1);
  __syncthreads();
  for (int i = threadIdx.x; i < N_NODES; i += blockDim.x) {
    int c = lh[i];
    if (c) atomicAdd(&counts[i], c);
  }
}

// ---------------- exclusive scan over 512 counts (1 block of 512) ----------------
__global__ void scan_k(const int* __restrict__ counts, int* __restrict__ offsets,
                       int* __restrict__ cursor) {
  __shared__ int tmp[N_NODES];
  const int t = threadIdx.x;
  const int c = counts[t];
  tmp[t] = c;
  __syncthreads();
  for (int d = 1; d < N_NODES; d <<= 1) {
    int add = (t >= d) ? tmp[t - d] : 0;
    __syncthreads();
    tmp[t] += add;
    __syncthreads();
  }
  offsets[t + 1] = tmp[t];
  if (t == 0) offsets[0] = 0;
  cursor[t] = tmp[t] - c;  // exclusive prefix
}

// ---------------- low-contention scatter: block bucketing + range reservation ----
// 64 blocks x 512 threads, 4096 edges per block.
__launch_bounds__(512)
__global__ void scatter2_k(const int* __restrict__ dst, int* __restrict__ cursor,
                           int* __restrict__ perm) {
  __shared__ int lhist[N_NODES];
  __shared__ int gb[N_NODES];
  const int t = threadIdx.x;
  const int c0 = blockIdx.x * 4096;
  lhist[t] = 0;
  __syncthreads();
  int d[8], r[8];
#pragma unroll
  for (int j = 0; j < 8; j++) {
    d[j] = dst[c0 + t + j * 512];
    r[j] = atomicAdd(&lhist[d[j]], 1);  // local rank within block
  }
  __syncthreads();
  gb[t] = atomicAdd(&cursor[t], lhist[t]);  // reserve contiguous range per node
  __syncthreads();
#pragma unroll
  for (int j = 0; j < 8; j++) perm[gb[d[j]] + r[j]] = c0 + t + j * 512;
}

// ---------------- layer-1 conv (small KK): edge-parallel, weights in LDS -------
template <int IN, int OUT, int INSTR, int OSTR>
__launch_bounds__(256)
__global__ void conv_k(const float* __restrict__ hprev, const float* __restrict__ ea,
                       const int* __restrict__ src, const int* __restrict__ perm,
                       const int* __restrict__ offsets, const float* __restrict__ W,
                       const float* __restrict__ bvec, const float* __restrict__ root,
                       const float* __restrict__ bias, float* __restrict__ hnext) {
  constexpr int KK = IN * OUT;
  __shared__ float Wt[KK * 8];
  __shared__ float red[4][OUT];
  const int node = blockIdx.x;

  for (int k = threadIdx.x; k < KK; k += blockDim.x) {
#pragma unroll
    for (int v = 0; v < 6; v++) Wt[k * 8 + v] = W[v * KK + k];
    Wt[k * 8 + 6] = bvec[k];
    Wt[k * 8 + 7] = 0.f;
  }
  __syncthreads();

  const int off = offsets[node];
  const int cnt = offsets[node + 1] - off;

  float acc[OUT];
#pragma unroll
  for (int o = 0; o < OUT; o++) acc[o] = 0.f;

  for (int t = threadIdx.x; t < cnt; t += blockDim.x) {
    const int e = perm[off + t];
    const float2 a01 = *reinterpret_cast<const float2*>(ea + e * 6);
    const float2 a23 = *reinterpret_cast<const float2*>(ea + e * 6 + 2);
    const float2 a45 = *reinterpret_cast<const float2*>(ea + e * 6 + 4);
    const float e0 = a01.x, e1 = a01.y, e2 = a23.x, e3 = a23.y, e4 = a45.x, e5 = a45.y;
    const int s = src[e];
    const float* hs = hprev + s * INSTR;
#pragma unroll
    for (int i = 0; i < IN; i++) {
      const float hsi = hs[i];
#pragma unroll
      for (int o = 0; o < OUT; o++) {
        const float4 w0 = *reinterpret_cast<const float4*>(&Wt[(i * OUT + o) * 8]);
        const float4 w1 = *reinterpret_cast<const float4*>(&Wt[(i * OUT + o) * 8 + 4]);
        float th = w1.z;
        th = fmaf(e0, w0.x, th);
        th = fmaf(e1, w0.y, th);
        th = fmaf(e2, w0.z, th);
        th = fmaf(e3, w0.w, th);
        th = fmaf(e4, w1.x, th);
        th = fmaf(e5, w1.y, th);
        acc[o] = fmaf(hsi, fmaxf(th, 0.f), acc[o]);
      }
    }
  }

  const int lane = threadIdx.x & 63;
  const int wid = threadIdx.x >> 6;
#pragma unroll
  for (int o = 0; o < OUT; o++) {
    float v = acc[o];
#pragma unroll
    for (int d = 32; d > 0; d >>= 1) v += __shfl_down(v, d, 64);
    if (lane == 0) red[wid][o] = v;
  }
  __syncthreads();

  if (threadIdx.x < OUT) {
    const int o = threadIdx.x;
    float sum = red[0][o] + red[1][o] + red[2][o] + red[3][o];
    float agg = sum / fmaxf((float)cnt, 1.f);
    float r = bias[o];
    for (int i = 0; i < IN; i++) r = fmaf(hprev[node * INSTR + i], root[i * OUT + o], r);
    hnext[node * OSTR + o] = fmaxf(agg + r, 0.f);
  }
}

// ---------------- big-KK conv: weights in REGISTERS, edges broadcast from LDS --
// Thread t (< ACTIVE=IN*TPI) owns pair slice (i = t/TPI, o in [o0, o0+OPT)),
// iterates over ALL edges of its node. Edges staged in double-buffered LDS.
template <int IN, int HP, int OUT, int OPT, int OSTR>
__launch_bounds__(256)
__global__ void convR_k(const float* __restrict__ hprev,   // [N][HP]
                        const float* __restrict__ ea, const int* __restrict__ srcA,
                        const int* __restrict__ perm, const int* __restrict__ offsets,
                        const float* __restrict__ W,       // [6][IN*OUT]
                        const float* __restrict__ bvec,    // [IN*OUT]
                        const float* __restrict__ root, const float* __restrict__ bias,
                        float* __restrict__ hnext) {       // [N][OSTR]
  constexpr int TPI = OUT / OPT;
  constexpr int ACTIVE = IN * TPI;
  constexpr int B = 64;
  constexpr int F2 = HP / 8;  // float2 loads per quarter-row
  __shared__ float2 eaS[2][B][4];
  __shared__ float hS[2][B][HP];
  __shared__ float pAcc[IN * OUT];

  const int tid = threadIdx.x;
  const int node = blockIdx.x;
  const int off = offsets[node];
  const int cnt = offsets[node + 1] - off;

  const int i_t = tid / TPI;
  const int o0 = (tid % TPI) * OPT;
  float w[OPT][7];
  float acc[OPT];
  if (tid < ACTIVE) {
#pragma unroll
    for (int k = 0; k < OPT; k++) {
      const int p = i_t * OUT + o0 + k;
#pragma unroll
      for (int v = 0; v < 6; v++) w[k][v] = W[v * (IN * OUT) + p];
      w[k][6] = bvec[p];
      acc[k] = 0.f;
    }
  }

  const int nb = (cnt + B - 1) / B;

  auto stage = [&](int batch, int buf) {
    const int b = tid >> 2, q = tid & 3;
    const int rem = cnt - batch * B;
    if (b < rem) {
      const int e = perm[off + batch * B + b];
      if (q < 3) eaS[buf][b][q] = *reinterpret_cast<const float2*>(ea + e * 6 + 2 * q);
      const int s = srcA[e];
      const float2* hr = reinterpret_cast<const float2*>(hprev + s * HP);
#pragma unroll
      for (int j = 0; j < F2; j++) {
        const int slot = q + 4 * j;
        *reinterpret_cast<float2*>(&hS[buf][b][2 * slot]) = hr[slot];
      }
    }
  };

  if (nb > 0) stage(0, 0);
  __syncthreads();
  for (int batch = 0; batch < nb; batch++) {
    const int cb = batch & 1;
    if (batch + 1 < nb) stage(batch + 1, cb ^ 1);
    if (tid < ACTIVE) {
      const int lim = min(B, cnt - batch * B);
#pragma unroll 2
      for (int b = 0; b < lim; b++) {
        const float2 a0 = eaS[cb][b][0];
        const float2 a1 = eaS[cb][b][1];
        const float2 a2 = eaS[cb][b][2];
        const float hv = hS[cb][b][i_t];
#pragma unroll
        for (int k = 0; k < OPT; k++) {
          float th = w[k][6];
          th = fmaf(a0.x, w[k][0], th);
          th = fmaf(a0.y, w[k][1], th);
          th = fmaf(a1.x, w[k][2], th);
          th = fmaf(a1.y, w[k][3], th);
          th = fmaf(a2.x, w[k][4], th);
          th = fmaf(a2.y, w[k][5], th);
          acc[k] = fmaf(hv, fmaxf(th, 0.f), acc[k]);
        }
      }
    }
    __syncthreads();
  }

  if (tid < ACTIVE) {
#pragma unroll
    for (int k = 0; k < OPT; k++) pAcc[i_t * OUT + o0 + k] = acc[k];
  }
  __syncthreads();
  if (tid < OUT) {
    const int o = tid;
    float s = 0.f;
    for (int i = 0; i < IN; i++) s += pAcc[i * OUT + o];
    const float agg = s / fmaxf((float)cnt, 1.f);
    float r = bias[o];
    for (int i = 0; i < IN; i++) r = fmaf(hprev[node * HP + i], root[i * OUT + o], r);
    hnext[node * OSTR + o] = fmaxf(agg + r, 0.f);
  }
}

// ---------------- CBT: pairwise L1 over h3 [512, 5] ----------------
__global__ void cbt_k(const float* __restrict__ h3, float* __restrict__ out) {
  __shared__ float sh[N_NODES * 5];
  for (int i = threadIdx.x; i < N_NODES * 5; i += blockDim.x) sh[i] = h3[i];
  __syncthreads();
  const int a = blockIdx.x;
  float ha0 = sh[a * 5 + 0], ha1 = sh[a * 5 + 1], ha2 = sh[a * 5 + 2],
        ha3 = sh[a * 5 + 3], ha4 = sh[a * 5 + 4];
  for (int b = threadIdx.x; b < N_NODES; b += blockDim.x) {
    float s = fabsf(sh[b * 5 + 0] - ha0) + fabsf(sh[b * 5 + 1] - ha1) +
              fabsf(sh[b * 5 + 2] - ha2) + fabsf(sh[b * 5 + 3] - ha3) +
              fabsf(sh[b * 5 + 4] - ha4);
    out[a * N_NODES + b] = s;
  }
}

extern "C" void kernel_launch(void* const* d_in, const int* in_sizes, int n_in,
                              void* d_out, int out_size, void* d_ws, size_t ws_size,
                              hipStream_t stream) {
  const float* x     = (const float*)d_in[0];
  const float* ea    = (const float*)d_in[1];
  const int*   ei    = (const int*)d_in[2];
  const float* W1    = (const float*)d_in[3];
  const float* b1    = (const float*)d_in[4];
  const float* root1 = (const float*)d_in[5];
  const float* bias1 = (const float*)d_in[6];
  const float* W2    = (const float*)d_in[7];
  const float* b2    = (const float*)d_in[8];
  const float* root2 = (const float*)d_in[9];
  const float* bias2 = (const float*)d_in[10];
  const float* W3    = (const float*)d_in[11];
  const float* b3    = (const float*)d_in[12];
  const float* root3 = (const float*)d_in[13];
  const float* bias3 = (const float*)d_in[14];

  const int* src = ei;
  const int* dst = ei + N_EDGES;

  char* ws = (char*)d_ws;
  int* counts  = (int*)(ws + 0);
  int* offsets = (int*)(ws + 8192);
  int* cursor  = (int*)(ws + 16384);
  int* perm    = (int*)(ws + 32768);                 // E ints = 1 MB
  float* h1    = (float*)(ws + 32768 + N_EDGES * 4); // [512][40]
  float* h2    = h1 + N_NODES * 40;                  // [512][24]
  float* h3    = h2 + N_NODES * 24;                  // [512][5]

  zero_k<<<2, 256, 0, stream>>>(counts, N_NODES);
  hist_k<<<256, 256, 0, stream>>>(dst, counts);
  scan_k<<<1, N_NODES, 0, stream>>>(counts, offsets, cursor);
  scatter2_k<<<N_EDGES / 4096, 512, 0, stream>>>(dst, cursor, perm);

  // layer 1: IN=1 OUT=36, edge-parallel (weights tiny), output stride 40
  conv_k<1, 36, 1, 40><<<N_NODES, 256, 0, stream>>>(x, ea, src, perm, offsets, W1, b1, root1, bias1, h1);
  // layer 2: IN=36 (stride 40) OUT=24, weights-in-registers, 4 o's per thread
  convR_k<36, 40, 24, 4, 24><<<N_NODES, 256, 0, stream>>>(h1, ea, src, perm, offsets, W2, b2, root2, bias2, h2);
  // layer 3: IN=24 OUT=5, weights-in-registers, 1 o per thread
  convR_k<24, 24, 5, 1, 5><<<N_NODES, 256, 0, stream>>>(h2, ea, src, perm, offsets, W3, b3, root3, bias3, h3);

  cbt_k<<<N_NODES, 256, 0, stream>>>(h3, (float*)d_out);
}

// Round 3
// 156.262 us; speedup vs baseline: 1.9040x; 1.0317x over previous
//
#include <hip/hip_runtime.h>

#define N_NODES 512
#define N_EDGES (512 * 512)

// ---------------- utility: zero int buffer ----------------
__global__ void zero_k(int* __restrict__ p, int n) {
  int i = blockIdx.x * blockDim.x + threadIdx.x;
  if (i < n) p[i] = 0;
}

// ---------------- histogram of dst ----------------
__global__ void hist_k(const int* __restrict__ dst, int* __restrict__ counts) {
  __shared__ int lh[N_NODES];
  for (int i = threadIdx.x; i < N_NODES; i += blockDim.x) lh[i] = 0;
  __syncthreads();
  const int stride = gridDim.x * blockDim.x;
  for (int e = blockIdx.x * blockDim.x + threadIdx.x; e < N_EDGES; e += stride)
    atomicAdd(&lh[dst[e]], 1);
  __syncthreads();
  for (int i = threadIdx.x; i < N_NODES; i += blockDim.x) {
    int c = lh[i];
    if (c) atomicAdd(&counts[i], c);
  }
}

// ---------------- exclusive scan over 512 counts (1 block of 512) ----------------
__global__ void scan_k(const int* __restrict__ counts, int* __restrict__ offsets,
                       int* __restrict__ cursor) {
  __shared__ int tmp[N_NODES];
  const int t = threadIdx.x;
  const int c = counts[t];
  tmp[t] = c;
  __syncthreads();
  for (int d = 1; d < N_NODES; d <<= 1) {
    int add = (t >= d) ? tmp[t - d] : 0;
    __syncthreads();
    tmp[t] += add;
    __syncthreads();
  }
  offsets[t + 1] = tmp[t];
  if (t == 0) offsets[0] = 0;
  cursor[t] = tmp[t] - c;  // exclusive prefix
}

// ---------------- low-contention scatter: block bucketing + range reservation ----
__launch_bounds__(512)
__global__ void scatter2_k(const int* __restrict__ dst, int* __restrict__ cursor,
                           int* __restrict__ perm) {
  __shared__ int lhist[N_NODES];
  __shared__ int gb[N_NODES];
  const int t = threadIdx.x;
  const int c0 = blockIdx.x * 4096;
  lhist[t] = 0;
  __syncthreads();
  int d[8], r[8];
#pragma unroll
  for (int j = 0; j < 8; j++) {
    d[j] = dst[c0 + t + j * 512];
    r[j] = atomicAdd(&lhist[d[j]], 1);
  }
  __syncthreads();
  gb[t] = atomicAdd(&cursor[t], lhist[t]);
  __syncthreads();
#pragma unroll
  for (int j = 0; j < 8; j++) perm[gb[d[j]] + r[j]] = c0 + t + j * 512;
}

// ---------------- layer-1 conv (IN=1): edge-parallel, weights in LDS -------
template <int IN, int OUT, int INSTR, int OSTR>
__launch_bounds__(256)
__global__ void conv_k(const float* __restrict__ hprev, const float* __restrict__ ea,
                       const int* __restrict__ src, const int* __restrict__ perm,
                       const int* __restrict__ offsets, const float* __restrict__ W,
                       const float* __restrict__ bvec, const float* __restrict__ root,
                       const float* __restrict__ bias, float* __restrict__ hnext) {
  constexpr int KK = IN * OUT;
  __shared__ float Wt[KK * 8];
  __shared__ float red[4][OUT];
  const int node = blockIdx.x;

  for (int k = threadIdx.x; k < KK; k += blockDim.x) {
#pragma unroll
    for (int v = 0; v < 6; v++) Wt[k * 8 + v] = W[v * KK + k];
    Wt[k * 8 + 6] = bvec[k];
    Wt[k * 8 + 7] = 0.f;
  }
  __syncthreads();

  const int off = offsets[node];
  const int cnt = offsets[node + 1] - off;

  float acc[OUT];
#pragma unroll
  for (int o = 0; o < OUT; o++) acc[o] = 0.f;

  for (int t = threadIdx.x; t < cnt; t += blockDim.x) {
    const int e = perm[off + t];
    const float2 a01 = *reinterpret_cast<const float2*>(ea + e * 6);
    const float2 a23 = *reinterpret_cast<const float2*>(ea + e * 6 + 2);
    const float2 a45 = *reinterpret_cast<const float2*>(ea + e * 6 + 4);
    const int s = src[e];
    const float* hs = hprev + s * INSTR;
#pragma unroll
    for (int i = 0; i < IN; i++) {
      const float hsi = hs[i];
#pragma unroll
      for (int o = 0; o < OUT; o++) {
        const float4 w0 = *reinterpret_cast<const float4*>(&Wt[(i * OUT + o) * 8]);
        const float4 w1 = *reinterpret_cast<const float4*>(&Wt[(i * OUT + o) * 8 + 4]);
        float th = w1.z;
        th = fmaf(a01.x, w0.x, th);
        th = fmaf(a01.y, w0.y, th);
        th = fmaf(a23.x, w0.z, th);
        th = fmaf(a23.y, w0.w, th);
        th = fmaf(a45.x, w1.x, th);
        th = fmaf(a45.y, w1.y, th);
        acc[o] = fmaf(hsi, fmaxf(th, 0.f), acc[o]);
      }
    }
  }

  const int lane = threadIdx.x & 63;
  const int wid = threadIdx.x >> 6;
#pragma unroll
  for (int o = 0; o < OUT; o++) {
    float v = acc[o];
#pragma unroll
    for (int d = 32; d > 0; d >>= 1) v += __shfl_down(v, d, 64);
    if (lane == 0) red[wid][o] = v;
  }
  __syncthreads();

  if (threadIdx.x < OUT) {
    const int o = threadIdx.x;
    float sum = red[0][o] + red[1][o] + red[2][o] + red[3][o];
    float agg = sum / fmaxf((float)cnt, 1.f);
    float r = bias[o];
    for (int i = 0; i < IN; i++) r = fmaf(hprev[node * INSTR + i], root[i * OUT + o], r);
    hnext[node * OSTR + o] = fmaxf(agg + r, 0.f);
  } else if (threadIdx.x < OSTR) {
    hnext[node * OSTR + threadIdx.x] = 0.f;  // zero pad columns
  }
}

// ---------------- big-KK conv v2: pairs across LANES, one wave per edge --------
// Lane l owns K_PER consecutive (i,o) pairs (spanning <=2 i values). Each wave
// processes its own disjoint 32-edge batches with a private double-buffered LDS
// pipeline (no block barrier in main loop). T14 async staging split.
template <int IN, int HP, int OUT, int OSTR>
__launch_bounds__(256, 2)
__global__ void convR2_k(const float* __restrict__ hprev,  // [N][HP]
                         const float* __restrict__ ea, const int* __restrict__ srcA,
                         const int* __restrict__ perm, const int* __restrict__ offsets,
                         const float* __restrict__ W,      // [6][IN*OUT]
                         const float* __restrict__ bvec,   // [IN*OUT]
                         const float* __restrict__ root, const float* __restrict__ bias,
                         float* __restrict__ hnext) {      // [N][OSTR]
  constexpr int NPAIR = IN * OUT;
  constexpr int K_PER = (NPAIR + 63) / 64;
  constexpr int B = 32;       // edges per batch
  constexpr int F4 = HP / 8;  // float4 per half-row

  __shared__ float eaS[4][2][B][6];
  __shared__ float hS[4][2][B][HP];
  __shared__ float pAcc[4][NPAIR];

  const int tid = threadIdx.x;
  const int wid = tid >> 6;
  const int l = tid & 63;
  const int node = blockIdx.x;
  const int off = offsets[node];
  const int cnt = offsets[node + 1] - off;

  // ---- per-lane pair slice init ----
  const int p0 = l * K_PER;
  const int i0 = min(p0, NPAIR - 1) / OUT;
  const int i1 = min(i0 + 1, IN - 1);
  float wgt[K_PER][6], wb[K_PER], mk[K_PER], acc[K_PER];
#pragma unroll
  for (int k = 0; k < K_PER; k++) {
    const int p = min(p0 + k, NPAIR - 1);
#pragma unroll
    for (int v = 0; v < 6; v++) wgt[k][v] = W[v * NPAIR + p];
    wb[k] = bvec[p];
    mk[k] = (p / OUT != i0) ? 1.f : 0.f;
    acc[k] = 0.f;
  }

  const int NB = (cnt + B - 1) / B;

  // ---- T14 async staging: load-to-reg early, ds_write late ----
  const int sb = l >> 1, sq = l & 1;
  float2 la0, la1, la2;
  float4 lh[F4];
  bool lok = false;

  auto stage_load = [&](int m) {
    const int pos = m * B + sb;
    lok = (pos < cnt);
    if (lok) {
      const int e = perm[off + pos];
      if (sq == 0) {
        const float2* er = reinterpret_cast<const float2*>(ea + (size_t)e * 6);
        la0 = er[0]; la1 = er[1]; la2 = er[2];
      }
      const int s = srcA[e];
      const float4* hr = reinterpret_cast<const float4*>(hprev + (size_t)s * HP);
#pragma unroll
      for (int j = 0; j < F4; j++) lh[j] = hr[sq * F4 + j];
    }
  };
  auto stage_write = [&](int buf) {
    if (lok) {
      if (sq == 0) {
        *reinterpret_cast<float2*>(&eaS[wid][buf][sb][0]) = la0;
        *reinterpret_cast<float2*>(&eaS[wid][buf][sb][2]) = la1;
        *reinterpret_cast<float2*>(&eaS[wid][buf][sb][4]) = la2;
      }
#pragma unroll
      for (int j = 0; j < F4; j++)
        *reinterpret_cast<float4*>(&hS[wid][buf][sb][sq * (HP / 2) + 4 * j]) = lh[j];
    }
  };

  if (wid < NB) { stage_load(wid); stage_write(0); }
  int buf = 0;
  for (int m = wid; m < NB; m += 4, buf ^= 1) {
    const bool more = (m + 4 < NB);
    if (more) stage_load(m + 4);
    const int lim = min(B, cnt - m * B);
    for (int b = 0; b < lim; b++) {
      const float2 a0 = *reinterpret_cast<const float2*>(&eaS[wid][buf][b][0]);
      const float2 a1 = *reinterpret_cast<const float2*>(&eaS[wid][buf][b][2]);
      const float2 a2 = *reinterpret_cast<const float2*>(&eaS[wid][buf][b][4]);
      const float hv0 = hS[wid][buf][b][i0];
      const float hd = hS[wid][buf][b][i1] - hv0;
#pragma unroll
      for (int k = 0; k < K_PER; k++) {
        float th = wb[k];
        th = fmaf(a0.x, wgt[k][0], th);
        th = fmaf(a0.y, wgt[k][1], th);
        th = fmaf(a1.x, wgt[k][2], th);
        th = fmaf(a1.y, wgt[k][3], th);
        th = fmaf(a2.x, wgt[k][4], th);
        th = fmaf(a2.y, wgt[k][5], th);
        const float hv = fmaf(mk[k], hd, hv0);
        acc[k] = fmaf(hv, fmaxf(th, 0.f), acc[k]);
      }
    }
    if (more) stage_write(buf ^ 1);
  }

  // ---- reduction: per-wave partials -> pair sums -> outputs ----
#pragma unroll
  for (int k = 0; k < K_PER; k++)
    if (p0 + k < NPAIR) pAcc[wid][p0 + k] = acc[k];
  __syncthreads();
  for (int p = tid; p < NPAIR; p += 256)
    pAcc[0][p] = pAcc[0][p] + pAcc[1][p] + pAcc[2][p] + pAcc[3][p];
  __syncthreads();
  if (tid < OUT) {
    const int o = tid;
    float s = 0.f;
    for (int i = 0; i < IN; i++) s += pAcc[0][i * OUT + o];
    const float agg = s / fmaxf((float)cnt, 1.f);
    float r = bias[o];
    for (int i = 0; i < IN; i++) r = fmaf(hprev[(size_t)node * HP + i], root[i * OUT + o], r);
    hnext[(size_t)node * OSTR + o] = fmaxf(agg + r, 0.f);
  }
}

// ---------------- CBT: pairwise L1 over h3 [512, 5] ----------------
__global__ void cbt_k(const float* __restrict__ h3, float* __restrict__ out) {
  __shared__ float sh[N_NODES * 5];
  for (int i = threadIdx.x; i < N_NODES * 5; i += blockDim.x) sh[i] = h3[i];
  __syncthreads();
  const int a = blockIdx.x;
  float ha0 = sh[a * 5 + 0], ha1 = sh[a * 5 + 1], ha2 = sh[a * 5 + 2],
        ha3 = sh[a * 5 + 3], ha4 = sh[a * 5 + 4];
  for (int b = threadIdx.x; b < N_NODES; b += blockDim.x) {
    float s = fabsf(sh[b * 5 + 0] - ha0) + fabsf(sh[b * 5 + 1] - ha1) +
              fabsf(sh[b * 5 + 2] - ha2) + fabsf(sh[b * 5 + 3] - ha3) +
              fabsf(sh[b * 5 + 4] - ha4);
    out[a * N_NODES + b] = s;
  }
}

extern "C" void kernel_launch(void* const* d_in, const int* in_sizes, int n_in,
                              void* d_out, int out_size, void* d_ws, size_t ws_size,
                              hipStream_t stream) {
  const float* x     = (const float*)d_in[0];
  const float* ea    = (const float*)d_in[1];
  const int*   ei    = (const int*)d_in[2];
  const float* W1    = (const float*)d_in[3];
  const float* b1    = (const float*)d_in[4];
  const float* root1 = (const float*)d_in[5];
  const float* bias1 = (const float*)d_in[6];
  const float* W2    = (const float*)d_in[7];
  const float* b2    = (const float*)d_in[8];
  const float* root2 = (const float*)d_in[9];
  const float* bias2 = (const float*)d_in[10];
  const float* W3    = (const float*)d_in[11];
  const float* b3    = (const float*)d_in[12];
  const float* root3 = (const float*)d_in[13];
  const float* bias3 = (const float*)d_in[14];

  const int* src = ei;
  const int* dst = ei + N_EDGES;

  char* ws = (char*)d_ws;
  int* counts  = (int*)(ws + 0);
  int* offsets = (int*)(ws + 8192);
  int* cursor  = (int*)(ws + 16384);
  int* perm    = (int*)(ws + 32768);                 // E ints = 1 MB
  float* h1    = (float*)(ws + 32768 + N_EDGES * 4); // [512][40]
  float* h2    = h1 + N_NODES * 40;                  // [512][24]
  float* h3    = h2 + N_NODES * 24;                  // [512][5]

  zero_k<<<2, 256, 0, stream>>>(counts, N_NODES);
  hist_k<<<256, 256, 0, stream>>>(dst, counts);
  scan_k<<<1, N_NODES, 0, stream>>>(counts, offsets, cursor);
  scatter2_k<<<N_EDGES / 4096, 512, 0, stream>>>(dst, cursor, perm);

  // layer 1: IN=1 OUT=36, edge-parallel, output stride 40 (zero-padded)
  conv_k<1, 36, 1, 40><<<N_NODES, 256, 0, stream>>>(x, ea, src, perm, offsets, W1, b1, root1, bias1, h1);
  // layer 2: IN=36 (stride 40) OUT=24: 864 pairs across lanes, K_PER=14
  convR2_k<36, 40, 24, 24><<<N_NODES, 256, 0, stream>>>(h1, ea, src, perm, offsets, W2, b2, root2, bias2, h2);
  // layer 3: IN=24 OUT=5: 120 pairs, K_PER=2
  convR2_k<24, 24, 5, 5><<<N_NODES, 256, 0, stream>>>(h2, ea, src, perm, offsets, W3, b3, root3, bias3, h3);

  cbt_k<<<N_NODES, 256, 0, stream>>>(h3, (float*)d_out);
}